// Round 1
// baseline (916.345 us; speedup 1.0000x reference)
//
#include <hip/hip_runtime.h>

#define B_ 32
#define F_ 256
#define T_ 2048
#define K_ 1024
#define M_ (B_*T_)   // 65536 points

#define BM 64        // points per block
#define BN 128       // codes per chunk
#define FC 32        // f per cs stage
#define NKC (K_/BN)  // 8
#define NFC (F_/FC)  // 8

// emb [K,F] -> embT [F,K] so code tiles stage f-major with coalesced loads
__global__ void k_transpose(const float* __restrict__ emb, float* __restrict__ embT) {
    int gid = blockIdx.x * 256 + threadIdx.x;   // over F*K, write-coalesced
    int k = gid & (K_ - 1);
    int f = gid >> 10;
    embT[gid] = emb[k * F_ + f];
}

__global__ void k_c2(const float* __restrict__ embT, double* __restrict__ c2) {
    int k = blockIdx.x * 256 + threadIdx.x;     // 0..1023, coalesced reads
    double s = 0.0;
    for (int f = 0; f < F_; ++f) {
        double v = (double)embT[f * K_ + k];
        s += v * v;
    }
    c2[k] = s;
}

__global__ __launch_bounds__(256, 2) void k_argmin(
    const float* __restrict__ x, const float* __restrict__ embT,
    const double* __restrict__ c2, int* __restrict__ idx_out,
    double* __restrict__ partials)
{
    __shared__ float xs[F_ * BM];   // 64 KB, xs[f*64 + t]
    __shared__ float cs[FC * BN];   // 16 KB, cs[ff*128 + c]

    const int tid = threadIdx.x;
    const int bid = blockIdx.x;
    const int b  = bid >> 5;          // 32 tiles of 64 t per batch
    const int t0 = (bid & 31) * BM;
    const int tx = tid & 15;          // code group (8 codes)
    const int ty = tid >> 4;          // row group (4 points)

    // stage x tile (fp32 exact) + accumulate sum of squares (fp64)
    double xsq = 0.0;
    {
        const int tq = tid & 15;
        const int fr = tid >> 4;
        for (int fo = 0; fo < 16; ++fo) {
            int f = fo * 16 + fr;
            const float4 v = *reinterpret_cast<const float4*>(
                x + (b * F_ + f) * T_ + t0 + tq * 4);
            xsq += (double)v.x * v.x + (double)v.y * v.y
                 + (double)v.z * v.z + (double)v.w * v.w;
            *reinterpret_cast<float4*>(&xs[f * BM + tq * 4]) = v;
        }
    }

    double minv[4] = {1e300, 1e300, 1e300, 1e300};
    int    mini[4] = {0, 0, 0, 0};

    for (int kc = 0; kc < NKC; ++kc) {
        const int k0 = kc * BN;
        double acc[4][8];
        #pragma unroll
        for (int r = 0; r < 4; ++r)
            #pragma unroll
            for (int c = 0; c < 8; ++c) acc[r][c] = 0.0;

        for (int fc = 0; fc < NFC; ++fc) {
            const int f0 = fc * FC;
            __syncthreads();   // protect cs from previous use (and xs staging on first pass)
            #pragma unroll
            for (int si = 0; si < 4; ++si) {
                int e  = si * 256 + tid;    // float4 id within 32x128 chunk
                int ff = e >> 5;
                int cq = e & 31;
                float4 v = *reinterpret_cast<const float4*>(
                    embT + (f0 + ff) * K_ + k0 + cq * 4);
                *reinterpret_cast<float4*>(&cs[ff * BN + cq * 4]) = v;
            }
            __syncthreads();

            #pragma unroll 4
            for (int ff = 0; ff < FC; ++ff) {
                float4 xv = *reinterpret_cast<const float4*>(&xs[(f0 + ff) * BM + ty * 4]);
                float4 cl = *reinterpret_cast<const float4*>(&cs[ff * BN + tx * 8]);
                float4 ch = *reinterpret_cast<const float4*>(&cs[ff * BN + tx * 8 + 4]);
                double xd[4] = {(double)xv.x, (double)xv.y, (double)xv.z, (double)xv.w};
                double cd[8] = {(double)cl.x, (double)cl.y, (double)cl.z, (double)cl.w,
                                (double)ch.x, (double)ch.y, (double)ch.z, (double)ch.w};
                #pragma unroll
                for (int r = 0; r < 4; ++r)
                    #pragma unroll
                    for (int c = 0; c < 8; ++c)
                        acc[r][c] = fma(xd[r], cd[c], acc[r][c]);
            }
        }

        // epilogue: q = c2 - 2*dot (a2 is constant per row -> argmin-invariant)
        #pragma unroll
        for (int c = 0; c < 8; ++c) {
            int k = k0 + tx * 8 + c;
            double c2v = c2[k];
            #pragma unroll
            for (int r = 0; r < 4; ++r) {
                double q = c2v - 2.0 * acc[r][c];
                if (q < minv[r]) { minv[r] = q; mini[r] = k; }  // strict < keeps lowest k
            }
        }
    }

    // reduce across the 16 tx lanes sharing the same 4 rows (lanes ty*16+tx in-wave)
    #pragma unroll
    for (int off = 1; off < 16; off <<= 1) {
        #pragma unroll
        for (int r = 0; r < 4; ++r) {
            double ov = __shfl_xor(minv[r], off);
            int    oi = __shfl_xor(mini[r], off);
            if (ov < minv[r] || (ov == minv[r] && oi < mini[r])) {
                minv[r] = ov; mini[r] = oi;
            }
        }
    }

    if (tx == 0) {
        #pragma unroll
        for (int r = 0; r < 4; ++r)
            idx_out[b * T_ + t0 + ty * 4 + r] = mini[r];
    }

    // block loss partial: sum of min q + sum of x^2  (dist = (a2 + q)/F summed later)
    __syncthreads();   // all compute reads of cs done before aliasing it
    double* redd = reinterpret_cast<double*>(cs);
    redd[tid] = xsq + ((tx == 0) ? (minv[0] + minv[1] + minv[2] + minv[3]) : 0.0);
    __syncthreads();
    for (int s = 128; s > 0; s >>= 1) {
        if (tid < s) redd[tid] += redd[tid + s];
        __syncthreads();
    }
    if (tid == 0) partials[bid] = redd[0];
}

__global__ void k_loss(const double* __restrict__ partials, float* __restrict__ out_losses) {
    __shared__ double redd[256];
    int tid = threadIdx.x;
    redd[tid] = partials[tid] + partials[tid + 256]
              + partials[tid + 512] + partials[tid + 768];
    __syncthreads();
    for (int s = 128; s > 0; s >>= 1) {
        if (tid < s) redd[tid] += redd[tid + s];
        __syncthreads();
    }
    if (tid == 0) {
        float loss = (float)(redd[0] / ((double)F_ * (double)M_));
        out_losses[0] = loss;   // loss_commit
        out_losses[1] = loss;   // loss_codebook (identical forward value)
    }
}

__global__ void k_gather(const float* __restrict__ emb, const int* __restrict__ idx,
                         float* __restrict__ out) {
    int gid = blockIdx.x * 256 + threadIdx.x;   // float4 id over [B,F,T/4]
    int t4 = gid & 511;           // T/4
    int f  = (gid >> 9) & 255;
    int b  = gid >> 17;
    const int* ip = idx + b * T_ + t4 * 4;
    float4 v;
    v.x = emb[ip[0] * F_ + f];
    v.y = emb[ip[1] * F_ + f];
    v.z = emb[ip[2] * F_ + f];
    v.w = emb[ip[3] * F_ + f];
    *reinterpret_cast<float4*>(out + (b * F_ + f) * T_ + t4 * 4) = v;
}

extern "C" void kernel_launch(void* const* d_in, const int* in_sizes, int n_in,
                              void* d_out, int out_size, void* d_ws, size_t ws_size,
                              hipStream_t stream) {
    const float* x   = (const float*)d_in[0];
    const float* emb = (const float*)d_in[1];
    float* out = (float*)d_out;

    // workspace layout (all recomputed every launch; ws is re-poisoned)
    float*  embT     = (float*)d_ws;                 // 256*1024 f32   (1 MB)
    double* c2       = (double*)(embT + F_ * K_);    // 1024 f64       (8 KB)
    int*    idx      = (int*)(c2 + K_);              // 65536 i32      (256 KB)
    double* partials = (double*)(idx + M_);          // 1024 f64       (8 KB)

    k_transpose<<<(F_ * K_) / 256, 256, 0, stream>>>(emb, embT);
    k_c2<<<K_ / 256, 256, 0, stream>>>(embT, c2);
    k_argmin<<<M_ / BM, 256, 0, stream>>>(x, embT, c2, idx, partials);
    k_loss<<<1, 256, 0, stream>>>(partials, out + (size_t)M_ * F_);
    k_gather<<<(M_ * (F_ / 4)) / 256, 256, 0, stream>>>(emb, idx, out);
}

// Round 4
// 203.261 us; speedup vs baseline: 4.5082x; 4.5082x over previous
//
#include <hip/hip_runtime.h>

#define B_ 32
#define F_ 256
#define T_ 2048
#define K_ 1024
#define M_ (B_*T_)     // 65536 points

#define MARGIN 0.45f   // covers 2*(fp16-screen tail ~0.1) + quant 0.0625 + slack
#define CAP 512

typedef _Float16 f16x8 __attribute__((ext_vector_type(8)));
typedef float f32x4 __attribute__((ext_vector_type(4)));

// ---- prep: emb [K,F] f32 -> cprep fp16 [K,F]; c2 (fp64 exact + fp32) ----
__global__ void k_prep(const float* __restrict__ emb, unsigned short* __restrict__ cprep,
                       double* __restrict__ c2d, float* __restrict__ c2f) {
    int k = blockIdx.x;      // 1024 blocks, 64 threads
    int l = threadIdx.x;
    float4 v = *reinterpret_cast<const float4*>(emb + k * F_ + l * 4);
    union { _Float16 h[4]; unsigned long long ll; } cv;
    cv.h[0] = (_Float16)v.x; cv.h[1] = (_Float16)v.y;
    cv.h[2] = (_Float16)v.z; cv.h[3] = (_Float16)v.w;
    *reinterpret_cast<unsigned long long*>(cprep + k * F_ + l * 4) = cv.ll;
    double s = (double)v.x * v.x + (double)v.y * v.y
             + (double)v.z * v.z + (double)v.w * v.w;
    #pragma unroll
    for (int d = 1; d < 64; d <<= 1) s += __shfl_xor(s, d);
    if (l == 0) { c2d[k] = s; c2f[k] = (float)s; }
}

// ---- main: fp16 MFMA screen (packed-int top-3 tracking) + fp64 rescore ----
__global__ __launch_bounds__(256, 2) void k_argmin(
    const float* __restrict__ x, const float* __restrict__ emb,
    const unsigned short* __restrict__ cprep,
    const double* __restrict__ c2d, const float* __restrict__ c2f,
    int* __restrict__ idx_out, double* __restrict__ partials)
{
    __shared__ __align__(16) unsigned char bbuf[2][8192];  // 16 codes x 256 f fp16, swizzled
    __shared__ int cand_cnt;
    __shared__ int cand_pk[CAP];
    __shared__ double cand_q[CAP];
    __shared__ int res_k[128];
    __shared__ double redbuf[256];

    const int tid = threadIdx.x;
    const int bid = blockIdx.x;           // 512 blocks
    const int b = bid >> 4;
    const int t_base = (bid & 15) * 128;
    const int w = tid >> 6;               // wave 0..3, owns points w*32..w*32+31
    const int l = tid & 63;
    const int row = l & 15;               // A row (point) / B col (code) within tile
    const int qd = l >> 4;                // k-quarter
    const int rsw = (row & 7) << 4;       // LDS XOR swizzle
    const int row512 = row * 512;

    if (tid == 0) cand_cnt = 0;

    // ---- load A (x) into fp16 fragments; per-lane partial sum(x^2) ----
    const float* xb = x + (size_t)b * (F_ * T_) + t_base + w * 32 + row
                    + (size_t)qd * 8 * T_;
    float xsql = 0.f, xsqh = 0.f;
    f16x8 ah0[8], ah1[8];
    #pragma unroll
    for (int s = 0; s < 8; ++s) {
        #pragma unroll
        for (int j = 0; j < 8; ++j) {
            size_t fo = (size_t)(s * 32 + j) * T_;
            float v0 = xb[fo];
            float v1 = xb[fo + 16];
            ah0[s][j] = (_Float16)v0;
            ah1[s][j] = (_Float16)v1;
            xsql = fmaf(v0, v0, xsql);
            xsqh = fmaf(v1, v1, xsqh);
        }
    }
    // full a2 per point: sum partials across the 4 qd groups (same row)
    float xl = xsql, xh = xsqh;
    xl += __shfl_xor(xl, 16); xl += __shfl_xor(xl, 32);
    xh += __shfl_xor(xh, 16); xh += __shfl_xor(xh, 32);
    // redistribute to C/D slot layout: slot r -> point qd*4 + r (lane qd*4+r holds it)
    float a2s[8];
    #pragma unroll
    for (int r = 0; r < 4; ++r) {
        a2s[r]     = __shfl(xl, qd * 4 + r);
        a2s[4 + r] = __shfl(xh, qd * 4 + r);
    }

    // ---- staging geometry (B tile: 16 codes x 256 f fp16 = 8 KB) ----
    const int srow = tid >> 5;            // 0..7
    const int sfc = tid & 31;
    const int sdst = srow * 512 + ((sfc * 16) ^ ((srow & 7) << 4));

    // prologue: stage tile 0 into buf 0
    {
        const unsigned short* p0 = cprep + srow * F_ + sfc * 8;
        uint4 a = *reinterpret_cast<const uint4*>(p0);
        uint4 c = *reinterpret_cast<const uint4*>(p0 + 8 * F_);
        *reinterpret_cast<uint4*>(&bbuf[0][sdst]) = a;
        *reinterpret_cast<uint4*>(&bbuf[0][sdst + 4096]) = c;
    }
    __syncthreads();

    int m1i[8], m2i[8], m3i[8];
    #pragma unroll
    for (int i = 0; i < 8; ++i) { m1i[i] = 0x7FFFFFFF; m2i[i] = 0x7FFFFFFF; m3i[i] = 0x7FFFFFFF; }

    for (int tile = 0; tile < 64; ++tile) {
        const int cur = tile & 1, nxt = cur ^ 1;
        uint4 st0, st1;
        if (tile < 63) {   // T14: issue next-tile loads early
            const unsigned short* p0 = cprep + ((tile + 1) * 16 + srow) * F_ + sfc * 8;
            st0 = *reinterpret_cast<const uint4*>(p0);
            st1 = *reinterpret_cast<const uint4*>(p0 + 8 * F_);
        }
        const int kk = tile * 16 + row;
        float c2v = c2f[kk];

        f32x4 acc0 = {0.f, 0.f, 0.f, 0.f};
        f32x4 acc1 = {0.f, 0.f, 0.f, 0.f};
        #pragma unroll
        for (int s = 0; s < 8; ++s) {
            int off = row512 + (((s * 64) + qd * 16) ^ rsw);
            f16x8 bh = *reinterpret_cast<const f16x8*>(&bbuf[cur][off]);
            acc0 = __builtin_amdgcn_mfma_f32_16x16x32_f16(ah0[s], bh, acc0, 0, 0, 0);
            acc1 = __builtin_amdgcn_mfma_f32_16x16x32_f16(ah1[s], bh, acc1, 0, 0, 0);
        }

        // epilogue: dist = a2 + c2 - 2*dot (>0), chop low 10 bits, pack code idx.
        // positive-float bit order == int order -> pure min/max int top-3 tracking.
        #pragma unroll
        for (int r = 0; r < 4; ++r) {
            {
                float q = fmaf(acc0[r], -2.0f, c2v + a2s[r]);
                int vi = (__float_as_int(q) & 0xFFFFFC00) | kk;
                int t1 = max(m1i[r], vi); m1i[r] = min(m1i[r], vi);
                int t2 = max(m2i[r], t1); m2i[r] = min(m2i[r], t1);
                m3i[r] = min(m3i[r], t2);
            }
            {
                float q = fmaf(acc1[r], -2.0f, c2v + a2s[4 + r]);
                int vi = (__float_as_int(q) & 0xFFFFFC00) | kk;
                int t1 = max(m1i[4 + r], vi); m1i[4 + r] = min(m1i[4 + r], vi);
                int t2 = max(m2i[4 + r], t1); m2i[4 + r] = min(m2i[4 + r], t1);
                m3i[4 + r] = min(m3i[4 + r], t2);
            }
        }

        if (tile < 63) {   // T14: write late
            *reinterpret_cast<uint4*>(&bbuf[nxt][sdst]) = st0;
            *reinterpret_cast<uint4*>(&bbuf[nxt][sdst + 4096]) = st1;
        }
        __syncthreads();
    }

    // ---- per-point group-reduce, provisional winner, candidate push ----
    double loss_acc = 0.0;
    #pragma unroll
    for (int i = 0; i < 8; ++i) {
        int gm = m1i[i];
        #pragma unroll
        for (int d = 1; d < 16; d <<= 1) { int o = __shfl_xor(gm, d); gm = min(gm, o); }
        float thr = __int_as_float(gm & 0xFFFFFC00) + MARGIN;
        bool in1 = __int_as_float(m1i[i] & 0xFFFFFC00) <= thr;
        bool in2 = __int_as_float(m2i[i] & 0xFFFFFC00) <= thr;   // NaN-safe: INT_MAX -> NaN -> false
        bool in3 = __int_as_float(m3i[i] & 0xFFFFFC00) <= thr;
        unsigned long long b1 = __ballot(in1), b2 = __ballot(in2), b3 = __ballot(in3);
        int sh = l & 48;
        int cnt = __popcll((b1 >> sh) & 0xFFFFull) + __popcll((b2 >> sh) & 0xFFFFull)
                + __popcll((b3 >> sh) & 0xFFFFull);
        int p = w * 32 + (i >> 2) * 16 + qd * 4 + (i & 3);
        if ((l & 15) == 0) {
            res_k[p] = gm & 1023;
            loss_acc += (double)__int_as_float((gm & 0xFFFFFC00) | 512);  // midpoint restore
        }
        if (cnt >= 2) {   // near-tie: push every in-margin candidate for exact rescore
            if (in1) { int s_ = atomicAdd(&cand_cnt, 1); if (s_ < CAP) cand_pk[s_] = (p << 10) | (m1i[i] & 1023); }
            if (in2) { int s_ = atomicAdd(&cand_cnt, 1); if (s_ < CAP) cand_pk[s_] = (p << 10) | (m2i[i] & 1023); }
            if (in3) { int s_ = atomicAdd(&cand_cnt, 1); if (s_ < CAP) cand_pk[s_] = (p << 10) | (m3i[i] & 1023); }
        }
    }
    __syncthreads();

    // ---- fp64 exact rescore (one wave per candidate; x tile is L2-hot) ----
    int total = cand_cnt; if (total > CAP) total = CAP;
    for (int ci = w; ci < total; ci += 4) {
        int pk = cand_pk[ci];
        int p = pk >> 10, k = pk & 1023;
        const float* xp = x + (size_t)b * (F_ * T_) + t_base + p;
        const float4 ev = *reinterpret_cast<const float4*>(emb + k * F_ + l * 4);
        double s = 0.0;
        s += (double)xp[(size_t)(l * 4 + 0) * T_] * (double)ev.x;
        s += (double)xp[(size_t)(l * 4 + 1) * T_] * (double)ev.y;
        s += (double)xp[(size_t)(l * 4 + 2) * T_] * (double)ev.z;
        s += (double)xp[(size_t)(l * 4 + 3) * T_] * (double)ev.w;
        #pragma unroll
        for (int d = 1; d < 64; d <<= 1) s += __shfl_xor(s, d);
        if (l == 0) cand_q[ci] = c2d[k] - 2.0 * s;   // per-point a2 const: argmin-equivalent
    }
    __syncthreads();

    // ---- owner scan: exact winner for rescored points; write idx ----
    if (tid < 128) {
        double bq = 1e300; int bk = -1; bool any = false;
        for (int ci = 0; ci < total; ++ci) {
            int pk = cand_pk[ci];
            if ((pk >> 10) == tid) {
                double q = cand_q[ci]; int k = pk & 1023;
                if (q < bq || (q == bq && k < bk)) { bq = q; bk = k; }
                any = true;
            }
        }
        idx_out[b * T_ + t_base + tid] = any ? bk : res_k[tid];
    }

    // ---- block loss partial (dist already includes a2) ----
    redbuf[tid] = loss_acc;
    __syncthreads();
    for (int s = 128; s > 0; s >>= 1) {
        if (tid < s) redbuf[tid] += redbuf[tid + s];
        __syncthreads();
    }
    if (tid == 0) partials[bid] = redbuf[0];
}

__global__ void k_loss(const double* __restrict__ partials, float* __restrict__ out_losses) {
    __shared__ double redd[256];
    int tid = threadIdx.x;
    redd[tid] = partials[tid] + partials[tid + 256];
    __syncthreads();
    for (int s = 128; s > 0; s >>= 1) {
        if (tid < s) redd[tid] += redd[tid + s];
        __syncthreads();
    }
    if (tid == 0) {
        float loss = (float)(redd[0] / ((double)F_ * (double)M_));
        out_losses[0] = loss;
        out_losses[1] = loss;
    }
}

__global__ void k_gather(const float* __restrict__ emb, const int* __restrict__ idx,
                         float* __restrict__ out) {
    int gid = blockIdx.x * 256 + threadIdx.x;   // float4 id over [B,F,T/4]
    int t4 = gid & 511;
    int f = (gid >> 9) & 255;
    int b = gid >> 17;
    const int4 ip = *reinterpret_cast<const int4*>(idx + b * T_ + t4 * 4);
    float4 v;
    v.x = emb[ip.x * F_ + f];
    v.y = emb[ip.y * F_ + f];
    v.z = emb[ip.z * F_ + f];
    v.w = emb[ip.w * F_ + f];
    *reinterpret_cast<float4*>(out + (b * F_ + f) * T_ + t4 * 4) = v;
}

extern "C" void kernel_launch(void* const* d_in, const int* in_sizes, int n_in,
                              void* d_out, int out_size, void* d_ws, size_t ws_size,
                              hipStream_t stream) {
    const float* x   = (const float*)d_in[0];
    const float* emb = (const float*)d_in[1];
    float* out = (float*)d_out;

    double* c2d = (double*)d_ws;                          // 8 KB
    double* partials = c2d + K_;                          // 4 KB
    unsigned short* cprep = (unsigned short*)(partials + 512);  // 512 KB
    float* c2f = (float*)(cprep + K_ * F_);               // 4 KB
    int* idx = (int*)(c2f + K_);                          // 256 KB

    k_prep<<<K_, 64, 0, stream>>>(emb, cprep, c2d, c2f);
    k_argmin<<<M_ / 128, 256, 0, stream>>>(x, emb, cprep, c2d, c2f, idx, partials);
    k_loss<<<1, 256, 0, stream>>>(partials, out + (size_t)M_ * F_);
    k_gather<<<(M_ * (F_ / 4)) / 256, 256, 0, stream>>>(emb, idx, out);
}